// Round 5
// baseline (791.064 us; speedup 1.0000x reference)
//
#include <hip/hip_runtime.h>
#include <math.h>

#define NT 13
#define RHW 57600  // 240*240
#define PIXB 8192  // pixels per chunk for minmax/hist
#define GRID 1024
#define TPB 256
#define NARR 8     // arrival-counter split per barrier

typedef unsigned long long ull;

struct Meta {
  const float* x[NT];
  int C[NT];
  int H[NT];
  float hsc[NT];            // (float)((double)H/240.0), host-computed
  int pixOff[NT + 1];       // per-tensor pixel offsets (sum HW)
  int nibOff[NT];           // u16 offsets into nibble cache (sum C*HW/4)
  int mmOff[NT + 1];        // (channel,chunk) item offsets
  int nchMM[NT];            // chunks per channel
  int pmOff[NT + 1];        // pmap item offsets (256 px per item)
};

__device__ __forceinline__ int segOf(const int* off, int b) {
  int t = 0;
  while (t + 1 < NT && b >= off[t + 1]) t++;
  return t;
}

// ---- software grid barrier: all GRID blocks resident (see __launch_bounds__ math) ----
__device__ __forceinline__ void gbar(unsigned* cnt8) {
  __syncthreads();
  if (threadIdx.x == 0) {
    __threadfence();  // release: make this block's writes visible device-wide
    __hip_atomic_fetch_add(&cnt8[blockIdx.x & (NARR - 1)], 1u,
                           __ATOMIC_RELAXED, __HIP_MEMORY_SCOPE_AGENT);
    for (;;) {
      unsigned s = 0;
#pragma unroll
      for (int i = 0; i < NARR; i++)
        s += __hip_atomic_load(&cnt8[i], __ATOMIC_RELAXED, __HIP_MEMORY_SCOPE_AGENT);
      if (s >= (unsigned)GRID) break;
      __builtin_amdgcn_s_sleep(2);
    }
    __threadfence();  // acquire: invalidate stale cache lines
  }
  __syncthreads();
}

// ---------------- P0 body: interior min/max over a pixel chunk ----------------
template <int HH>
__device__ __forceinline__ void mm_body(const float* __restrict__ ch, int pix0, int pix1,
                                        float& mn, float& mx) {
  constexpr int W = HH, H = HH;
  int i40 = pix0 >> 2, i41 = pix1 >> 2;
  for (int i4 = i40 + (int)threadIdx.x; i4 < i41; i4 += 2 * TPB) {
    int i4b = i4 + TPB;
    float4 v0 = reinterpret_cast<const float4*>(ch)[i4];
    float4 v1 = make_float4(0.f, 0.f, 0.f, 0.f);
    bool has1 = i4b < i41;
    if (has1) v1 = reinterpret_cast<const float4*>(ch)[i4b];
#pragma unroll
    for (int j = 0; j < 4; j++) {
      int idx = i4 * 4 + j;
      int h = idx / W, w = idx - h * W;  // compile-time magic div
      bool ok = h > 0 && h < (H - 1) && w > 0 && w < (W - 1);
      float f = (j == 0) ? v0.x : (j == 1) ? v0.y : (j == 2) ? v0.z : v0.w;
      if (ok) { mn = fminf(mn, f); mx = fmaxf(mx, f); }
    }
    if (has1) {
#pragma unroll
      for (int j = 0; j < 4; j++) {
        int idx = i4b * 4 + j;
        int h = idx / W, w = idx - h * W;
        bool ok = h > 0 && h < (H - 1) && w > 0 && w < (W - 1);
        float f = (j == 0) ? v1.x : (j == 1) ? v1.y : (j == 2) ? v1.z : v1.w;
        if (ok) { mn = fminf(mn, f); mx = fmaxf(mx, f); }
      }
    }
  }
}

// ---------------- P1 body: dual 6-bin histogram + nibble cache write ----------------
template <int HH>
__device__ __forceinline__ void hist_body(const float* __restrict__ ch,
                                          unsigned short* __restrict__ nb,
                                          int pix0, int pix1, float mn, float invd,
                                          ull& cbin, ull& clut) {
  constexpr int W = HH, H = HH;
  int i40 = pix0 >> 2, i41 = pix1 >> 2;
  int nIter = (i41 - i40 + TPB - 1) / TPB;
  for (int it = 0; it < nIter; ++it) {
    int i4 = i40 + it * TPB + (int)threadIdx.x;
    bool valid = i4 < i41;
    float4 v = make_float4(0.f, 0.f, 0.f, 0.f);
    if (valid) v = reinterpret_cast<const float4*>(ch)[i4];
    unsigned pack = 0;
#pragma unroll
    for (int j = 0; j < 4; j++) {
      int idx = i4 * 4 + j;
      int h = idx / W, w = idx - h * W;
      bool intr = h > 0 && h < (H - 1) && w > 0 && w < (W - 1);
      float f = (j == 0) ? v.x : (j == 1) ? v.y : (j == 2) ? v.z : v.w;
      float vv = (f - mn) * invd * 256.0f;
      int bin = (int)(vv * 0.0234375f);  // * (6/256)
      bin = bin < 0 ? 0 : (bin > 5 ? 5 : bin);
      float tt = vv * 6.0f - 1.0f;
      int li = (int)tt;                  // trunc toward zero, matches astype(int32)
      li = li < 0 ? 0 : (li > 5 ? 5 : li);
      bool ok = valid && intr;
      cbin += (ull)ok << (bin * 10);
      clut += (ull)ok << (li * 10);
      pack |= (unsigned)(intr ? li : 7) << (4 * j);  // border -> LUT slot 7
    }
    if (valid) nb[i4] = (unsigned short)pack;
  }
}

// ---------------- per-channel 8-slot LUT (slots 0-5 interior, 7 border) ----------------
__device__ __forceinline__ void buildLut(int c, int H, int HW, int cb, int nch,
                                         const float* __restrict__ cpart,
                                         const unsigned* __restrict__ hpart, float* sLut) {
  float mn = INFINITY, mx = -INFINITY;
  unsigned hh[12];
#pragma unroll
  for (int j = 0; j < 12; j++) hh[j] = 0u;
  for (int k = 0; k < nch; k++) {
    mn = fminf(mn, cpart[2 * (cb + k)]);
    mx = fmaxf(mx, cpart[2 * (cb + k) + 1]);
#pragma unroll
    for (int j = 0; j < 12; j++) hh[j] += hpart[12 * (cb + k) + j];
  }
  mn = fminf(mn, 0.f); mx = fmaxf(mx, 0.f);   // fold border zeros
  float d = mx - mn;
  float invd = d > 0.f ? 1.0f / d : 0.f;
  float fHW = (float)HW;
  int nbp = 4 * H - 4;  // border pixel count (W==H)
  float vb = (0.f - mn) * invd * 256.0f;
  int bin_b = (int)(vb * 0.0234375f);
  bin_b = bin_b < 0 ? 0 : (bin_b > 5 ? 5 : bin_b);
  float ttb = vb * 6.0f - 1.0f;
  int lib = (int)ttb;
  lib = lib < 0 ? 0 : (lib > 5 ? 5 : lib);
  hh[bin_b] += (unsigned)nbp;   // reconstruct full-mask histograms
  hh[6 + lib] += (unsigned)nbp;
  float hl[6];
#pragma unroll
  for (int j = 0; j < 6; j++) hl[j] = -logf((float)hh[j] / fHW + 1e-4f);
  float mn2 = INFINITY, mx2 = -INFINITY, sum2 = 0.f;
#pragma unroll
  for (int j = 0; j < 6; j++) {
    unsigned cc = hh[6 + j];
    if (cc) { mn2 = fminf(mn2, hl[j]); mx2 = fmaxf(mx2, hl[j]); sum2 += (float)cc * hl[j]; }
  }
  float d2 = mx2 - mn2;
  float RL[6];
  if (d2 > 0.f) {
    float meanN = (sum2 / fHW - mn2) / d2;
    float w = 1.0f - meanN; w *= w;
#pragma unroll
    for (int j = 0; j < 6; j++) RL[j] = (hl[j] - mn2) / d2 * w;
  } else {
#pragma unroll
    for (int j = 0; j < 6; j++) RL[j] = 0.f;
  }
  float LUT[7];
  if (c == 0) {
    float mnr = INFINITY, mxr = -INFINITY, sumr = 0.f;
#pragma unroll
    for (int j = 0; j < 6; j++) {
      unsigned cc = hh[6 + j];
      if (cc) { mnr = fminf(mnr, RL[j]); mxr = fmaxf(mxr, RL[j]); sumr += (float)cc * RL[j]; }
    }
    float dr = mxr - mnr;
    if (dr > 0.f) {
      float meanr = sumr / fHW;
      float wp = mxr - meanr; wp *= wp;
#pragma unroll
      for (int j = 0; j < 6; j++) LUT[j] = (RL[j] - mnr) / dr * wp;
      LUT[6] = LUT[lib];
    } else {
#pragma unroll
      for (int j = 0; j < 7; j++) LUT[j] = 0.f;
    }
  } else {
    float mnr = 0.f, mxr = 0.f, sumr = 0.f;
#pragma unroll
    for (int j = 0; j < 6; j++) {
      int cc = (int)hh[6 + j] - (j == lib ? nbp : 0);
      if (cc > 0) { mnr = fminf(mnr, RL[j]); mxr = fmaxf(mxr, RL[j]); sumr += (float)cc * RL[j]; }
    }
    float dr = mxr - mnr;
    if (dr > 0.f) {
      float meanr = sumr / fHW;
      float wp = mxr - meanr; wp *= wp;
#pragma unroll
      for (int j = 0; j < 6; j++) LUT[j] = (RL[j] - mnr) / dr * wp;
      LUT[6] = (0.f - mnr) / dr * wp;
    } else {
#pragma unroll
      for (int j = 0; j < 7; j++) LUT[j] = 0.f;
    }
  }
#pragma unroll
  for (int j = 0; j < 6; j++) sLut[c * 8 + j] = LUT[j];
  sLut[c * 8 + 6] = LUT[6];
  sLut[c * 8 + 7] = LUT[6];
}

// ================= the whole pipeline in one persistent kernel =================
__global__ __launch_bounds__(TPB, 4) void k_all(
    Meta m, unsigned* bar,
    float* __restrict__ cpart, unsigned* __restrict__ hpart, unsigned short* __restrict__ nib,
    float* __restrict__ pmaps, float* __restrict__ ppart, float* __restrict__ mmaps,
    float* __restrict__ rpart, float* __restrict__ fusedm, float* __restrict__ fpart,
    float* __restrict__ out) {
  __shared__ float sLut[4096];       // 16 KB (P2)
  __shared__ float sAcc[4][256];     // 4 KB (P2 reduce)
  __shared__ unsigned swh[4][12];    // (P1)
  __shared__ float sA[16], sB[16], sC[16];
  int tid = threadIdx.x;
  int wid = tid >> 6, lane = tid & 63;

  // ---------- P0: per-(channel,chunk) interior min/max partials ----------
  for (int b = blockIdx.x; b < m.mmOff[NT]; b += GRID) {
    int t = segOf(m.mmOff, b);
    int local = b - m.mmOff[t];
    int nch = m.nchMM[t];
    int c = local / nch, k = local - c * nch;
    int HW = m.H[t] * m.H[t];
    const float* ch = m.x[t] + (size_t)c * HW;
    int pix0 = k * PIXB, pix1 = min(pix0 + PIXB, HW);
    float mn = INFINITY, mx = -INFINITY;
    switch (m.H[t]) {
      case 224: mm_body<224>(ch, pix0, pix1, mn, mx); break;
      case 112: mm_body<112>(ch, pix0, pix1, mn, mx); break;
      case 56:  mm_body<56>(ch, pix0, pix1, mn, mx); break;
      case 28:  mm_body<28>(ch, pix0, pix1, mn, mx); break;
      default:  mm_body<14>(ch, pix0, pix1, mn, mx); break;
    }
#pragma unroll
    for (int o = 32; o > 0; o >>= 1) {
      mn = fminf(mn, __shfl_down(mn, o));
      mx = fmaxf(mx, __shfl_down(mx, o));
    }
    if (lane == 0) { sA[wid] = mn; sB[wid] = mx; }
    __syncthreads();
    if (tid == 0) {
      for (int i = 1; i < 4; i++) { mn = fminf(mn, sA[i]); mx = fmaxf(mx, sB[i]); }
      cpart[2 * b] = mn; cpart[2 * b + 1] = mx;
    }
    __syncthreads();
  }
  gbar(&bar[0 * NARR]);

  // ---------- P1: histograms + nibble cache ----------
  for (int b = blockIdx.x; b < m.mmOff[NT]; b += GRID) {
    int t = segOf(m.mmOff, b);
    int local = b - m.mmOff[t];
    int nch = m.nchMM[t];
    int c = local / nch, k = local - c * nch;
    int H = m.H[t], HW = H * H;
    const float* ch = m.x[t] + (size_t)c * HW;
    int cb = m.mmOff[t] + c * nch;
    float mn = INFINITY, mx = -INFINITY;
    for (int kk = 0; kk < nch; kk++) {
      mn = fminf(mn, cpart[2 * (cb + kk)]);
      mx = fmaxf(mx, cpart[2 * (cb + kk) + 1]);
    }
    mn = fminf(mn, 0.f); mx = fmaxf(mx, 0.f);
    float d = mx - mn;
    float invd = d > 0.f ? 1.0f / d : 0.f;
    unsigned short* nb = nib + m.nibOff[t] + (size_t)c * (HW >> 2);
    int pix0 = k * PIXB, pix1 = min(pix0 + PIXB, HW);
    ull cbin = 0ull, clut = 0ull;
    switch (H) {
      case 224: hist_body<224>(ch, nb, pix0, pix1, mn, invd, cbin, clut); break;
      case 112: hist_body<112>(ch, nb, pix0, pix1, mn, invd, cbin, clut); break;
      case 56:  hist_body<56>(ch, nb, pix0, pix1, mn, invd, cbin, clut); break;
      case 28:  hist_body<28>(ch, nb, pix0, pix1, mn, invd, cbin, clut); break;
      default:  hist_body<14>(ch, nb, pix0, pix1, mn, invd, cbin, clut); break;
    }
    unsigned pk[6];
#pragma unroll
    for (int j = 0; j < 6; j++)
      pk[j] = (unsigned)((cbin >> (10 * j)) & 1023ull) |
              ((unsigned)((clut >> (10 * j)) & 1023ull) << 16);
#pragma unroll
    for (int o = 32; o > 0; o >>= 1) {
#pragma unroll
      for (int j = 0; j < 6; j++) pk[j] += __shfl_down(pk[j], o);
    }
    if (lane == 0) {
#pragma unroll
      for (int j = 0; j < 6; j++) { swh[wid][j] = pk[j] & 0xffffu; swh[wid][6 + j] = pk[j] >> 16; }
    }
    __syncthreads();
    if (tid < 12)
      hpart[12 * b + tid] = swh[0][tid] + swh[1][tid] + swh[2][tid] + swh[3][tid];
    __syncthreads();
  }
  gbar(&bar[1 * NARR]);

  // ---------- P2: p map from nibble cache (LUT in LDS) ----------
  for (int b = blockIdx.x; b < m.pmOff[NT]; b += GRID) {
    int t = segOf(m.pmOff, b);
    int blk = b - m.pmOff[t];
    int C = m.C[t], H = m.H[t], HW = H * H, i4n = HW >> 2;
    int nch = m.nchMM[t];
    for (int c = tid; c < C; c += TPB)
      buildLut(c, H, HW, m.mmOff[t] + c * nch, nch, cpart, hpart, sLut);
    __syncthreads();
    int i4 = blk * 64 + lane;
    bool act = i4 < i4n;
    float a0 = 0.f, a1 = 0.f, a2 = 0.f, a3 = 0.f;
    if (act) {
      const unsigned short* nb = nib + m.nibOff[t] + i4;
      int cpw = C >> 2;
      int c0 = wid * cpw, c1 = c0 + cpw;
#pragma unroll 4
      for (int c = c0; c < c1; ++c) {
        unsigned n = nb[(size_t)c * i4n];
        a0 += sLut[c * 8 + (int)(n & 7u)];
        a1 += sLut[c * 8 + (int)((n >> 4) & 7u)];
        a2 += sLut[c * 8 + (int)((n >> 8) & 7u)];
        a3 += sLut[c * 8 + (int)((n >> 12) & 7u)];
      }
    }
    *reinterpret_cast<float4*>(&sAcc[wid][lane * 4]) = make_float4(a0, a1, a2, a3);
    __syncthreads();
    if (wid == 0) {
      float bmn = INFINITY, bmx = -INFINITY;
      if (act) {
        float t0 = 0.f, t1 = 0.f, t2 = 0.f, t3 = 0.f;
#pragma unroll
        for (int w = 0; w < 4; w++) {  // ascending w == ascending channel blocks
          const float* s = &sAcc[w][lane * 4];
          t0 += s[0]; t1 += s[1]; t2 += s[2]; t3 += s[3];
        }
        *reinterpret_cast<float4*>(pmaps + (size_t)m.pixOff[t] + (size_t)i4 * 4) =
            make_float4(t0, t1, t2, t3);
        bmn = fminf(fminf(t0, t1), fminf(t2, t3));
        bmx = fmaxf(fmaxf(t0, t1), fmaxf(t2, t3));
      }
#pragma unroll
      for (int o = 32; o > 0; o >>= 1) {
        bmn = fminf(bmn, __shfl_down(bmn, o));
        bmx = fmaxf(bmx, __shfl_down(bmx, o));
      }
      if (lane == 0) { ppart[2 * b] = bmn; ppart[2 * b + 1] = bmx; }
    }
    __syncthreads();
  }
  gbar(&bar[2 * NARR]);

  // ---------- P3: bilinear resize + norm ----------
  for (int b = blockIdx.x; b < NT * 225; b += GRID) {
    int t = b / 225, blk = b - t * 225;
    if (wid == 0) {
      int n = m.pmOff[t + 1] - m.pmOff[t];
      const float* pp = ppart + (size_t)m.pmOff[t] * 2;
      float mn = INFINITY, mx = -INFINITY;
      for (int i = lane; i < n; i += 64) { mn = fminf(mn, pp[2 * i]); mx = fmaxf(mx, pp[2 * i + 1]); }
#pragma unroll
      for (int o = 32; o > 0; o >>= 1) {
        mn = fminf(mn, __shfl_down(mn, o));
        mx = fmaxf(mx, __shfl_down(mx, o));
      }
      if (lane == 0) {
        float d = mx - mn;
        sA[0] = mn; sA[1] = d > 0.f ? 1.0f / d : 0.f;
      }
    }
    __syncthreads();
    int pix = blk * 256 + tid;  // 225*256 == 57600 exactly
    int H = m.H[t], W = H;
    const float* p = pmaps + m.pixOff[t];
    float mn = sA[0], a = sA[1];
    int oy = pix / 240, ox = pix - oy * 240;
    float hs = m.hsc[t];
    float sy = ((float)oy + 0.5f) * hs - 0.5f;
    float sx = ((float)ox + 0.5f) * hs - 0.5f;
    float fy0 = floorf(sy), fx0 = floorf(sx);
    float fy = sy - fy0, fx = sx - fx0;
    int iy0 = (int)fy0, ix0 = (int)fx0;
    int y0 = iy0 < 0 ? 0 : (iy0 > H - 1 ? H - 1 : iy0);
    int y1 = iy0 + 1 < 0 ? 0 : (iy0 + 1 > H - 1 ? H - 1 : iy0 + 1);
    int x0 = ix0 < 0 ? 0 : (ix0 > W - 1 ? W - 1 : ix0);
    int x1 = ix0 + 1 < 0 ? 0 : (ix0 + 1 > W - 1 ? W - 1 : ix0 + 1);
    float v00 = p[y0 * W + x0], v01 = p[y0 * W + x1];
    float v10 = p[y1 * W + x0], v11 = p[y1 * W + x1];
    float r = (1.f - fy) * ((1.f - fx) * v00 + fx * v01) + fy * ((1.f - fx) * v10 + fx * v11);
    float mv = (r - mn) * a;
    mmaps[(size_t)t * RHW + pix] = mv;
    float bmn = mv, bmx = mv, bsm = mv;
#pragma unroll
    for (int o = 32; o > 0; o >>= 1) {
      bmn = fminf(bmn, __shfl_down(bmn, o));
      bmx = fmaxf(bmx, __shfl_down(bmx, o));
      bsm += __shfl_down(bsm, o);
    }
    if (lane == 0) { sB[wid] = bmn; sB[4 + wid] = bmx; sB[8 + wid] = bsm; }
    __syncthreads();
    if (tid == 0) {
      for (int i = 1; i < 4; i++) {
        bmn = fminf(bmn, sB[i]); bmx = fmaxf(bmx, sB[4 + i]); bsm += sB[8 + i];
      }
      float* rp = rpart + ((size_t)t * 225 + blk) * 3;
      rp[0] = bmn; rp[1] = bmx; rp[2] = bsm;
    }
    __syncthreads();
  }
  gbar(&bar[3 * NARR]);

  // ---------- P4: fuse group ----------
  for (int b = blockIdx.x; b < 5 * 225; b += GRID) {
    int g = b / 225, blk = b - g * 225;
    const int gs[6] = {0, 2, 4, 7, 10, 13};
    int nt = gs[g + 1] - gs[g];
    if (wid < nt) {
      int t = gs[g] + wid;
      const float* rp = rpart + (size_t)t * 225 * 3;
      float mn = INFINITY, mx = -INFINITY, sm = 0.f;
      for (int i = lane; i < 225; i += 64) {
        mn = fminf(mn, rp[3 * i]); mx = fmaxf(mx, rp[3 * i + 1]); sm += rp[3 * i + 2];
      }
#pragma unroll
      for (int o = 32; o > 0; o >>= 1) {
        mn = fminf(mn, __shfl_down(mn, o));
        mx = fmaxf(mx, __shfl_down(mx, o));
        sm += __shfl_down(sm, o);
      }
      if (lane == 0) {
        float d = mx - mn;
        if (d > 0.f) {
          float mean = sm * (1.0f / 57600.0f);
          float w = mx - mean; w *= w;
          sA[wid] = mn; sB[wid] = d; sC[wid] = w;
        } else {
          sA[wid] = 0.f; sB[wid] = 0.f; sC[wid] = 0.f;
        }
      }
    }
    __syncthreads();
    int pix = blk * 256 + tid;
    float acc = 0.f;
    for (int k2 = 0; k2 < nt; k2++) {
      int t = gs[g] + k2;
      if (sB[k2] > 0.f) acc += (mmaps[(size_t)t * RHW + pix] - sA[k2]) / sB[k2] * sC[k2];
    }
    fusedm[(size_t)g * RHW + pix] = acc;
    float bmn = acc, bmx = acc;
#pragma unroll
    for (int o = 32; o > 0; o >>= 1) {
      bmn = fminf(bmn, __shfl_down(bmn, o));
      bmx = fmaxf(bmx, __shfl_down(bmx, o));
    }
    if (lane == 0) { sA[8 + wid] = bmn; sB[8 + wid] = bmx; }
    __syncthreads();
    if (tid == 0) {
      for (int i = 1; i < 4; i++) { bmn = fminf(bmn, sA[8 + i]); bmx = fmaxf(bmx, sB[8 + i]); }
      float* fp = fpart + ((size_t)g * 225 + blk) * 2;
      fp[0] = bmn; fp[1] = bmx;
    }
    __syncthreads();
  }
  gbar(&bar[4 * NARR]);

  // ---------- P5: final outputs ----------
  for (int b = blockIdx.x; b < 225; b += GRID) {
    for (int g = wid; g < 5; g += 4) {
      const float* fp = fpart + (size_t)g * 225 * 2;
      float mn = INFINITY, mx = -INFINITY;
      for (int i = lane; i < 225; i += 64) {
        mn = fminf(mn, fp[2 * i]); mx = fmaxf(mx, fp[2 * i + 1]);
      }
#pragma unroll
      for (int o = 32; o > 0; o >>= 1) {
        mn = fminf(mn, __shfl_down(mn, o));
        mx = fmaxf(mx, __shfl_down(mx, o));
      }
      if (lane == 0) {
        float d = mx - mn;
        sA[g] = mn; sB[g] = d > 0.f ? 256.0f / d : 0.f;
      }
    }
    __syncthreads();
    int pix = b * 256 + tid;
    float acc = 0.f;
    float* out2 = out + RHW;
#pragma unroll
    for (int g = 0; g < 5; g++) {
      float v = (fusedm[(size_t)g * RHW + pix] - sA[g]) * sB[g];
      out2[(size_t)pix * 5 + g] = v;
      acc += v;
    }
    out[pix] = acc;
    __syncthreads();
  }
}

extern "C" void kernel_launch(void* const* d_in, const int* in_sizes, int n_in,
                              void* d_out, int out_size, void* d_ws, size_t ws_size,
                              hipStream_t stream) {
  static const int Cs[NT] = {64, 64, 128, 128, 256, 256, 256, 512, 512, 512, 512, 512, 512};
  static const int Hs[NT] = {224, 224, 112, 112, 56, 56, 56, 28, 28, 28, 14, 14, 14};
  Meta m;
  int po = 0, mmb = 0, pmb = 0, nibTot = 0;
  for (int t = 0; t < NT; t++) {
    m.x[t] = (const float*)d_in[t];
    m.C[t] = Cs[t]; m.H[t] = Hs[t];
    m.hsc[t] = (float)((double)Hs[t] / 240.0);
    int HW = Hs[t] * Hs[t];
    m.pixOff[t] = po; po += HW;
    m.nibOff[t] = nibTot; nibTot += Cs[t] * (HW >> 2);
    m.mmOff[t] = mmb;
    m.nchMM[t] = (HW + PIXB - 1) / PIXB;
    mmb += Cs[t] * m.nchMM[t];
    m.pmOff[t] = pmb;
    pmb += (HW + 255) / 256;
  }
  m.pixOff[NT] = po; m.mmOff[NT] = mmb; m.pmOff[NT] = pmb;

  size_t off = 0;
  auto a16 = [](size_t x) { return (x + 15) & ~(size_t)15; };
#define WALLOC(var, type, count) type* var = (type*)((char*)d_ws + off); off = a16(off + sizeof(type) * (size_t)(count));
  WALLOC(bar, unsigned, 8 * NARR)
  WALLOC(cpart, float, 2 * mmb)
  WALLOC(hpart, unsigned, 12 * mmb)
  WALLOC(nib, unsigned short, nibTot)
  WALLOC(ppart, float, 2 * pmb)
  WALLOC(rpart, float, NT * 225 * 3)
  WALLOC(fpart, float, 5 * 225 * 2)
  WALLOC(pmaps, float, po)
  WALLOC(mmaps, float, NT * RHW)
  WALLOC(fusedm, float, 5 * RHW)
#undef WALLOC

  hipMemsetAsync(bar, 0, 8 * NARR * sizeof(unsigned), stream);
  hipLaunchKernelGGL(k_all, dim3(GRID), dim3(TPB), 0, stream,
                     m, bar, cpart, hpart, nib, pmaps, ppart, mmaps, rpart, fusedm, fpart,
                     (float*)d_out);
}

// Round 6
// 75.551 us; speedup vs baseline: 10.4706x; 10.4706x over previous
//
#include <hip/hip_runtime.h>
#include <math.h>

#define NT 13
#define RHW 57600  // 240*240

typedef unsigned long long ull;

struct Meta {
  const float* x[NT];
  int C[NT];
  int H[NT];
  float hsc[NT];            // (float)((double)H/240.0), host-computed
  int chanOff[NT + 1];      // global channel index offsets
  int pixOff[NT + 1];       // per-tensor pixel offsets
  int nibOff[NT];           // u16 offsets into nibble cache (C*HW/4 per tensor)
  int pmOff[NT + 1];        // pmap block offsets (256 px per block)
};

__device__ __forceinline__ int segOf(const int* off, int b) {
  int t = 0;
  while (t + 1 < NT && b >= off[t + 1]) t++;
  return t;
}

// ---------------- K1 pass A: interior min/max over one channel ----------------
template <int HH>
__device__ __forceinline__ void mmA(const float* __restrict__ ch, float& mn, float& mx) {
  constexpr int W = HH, H = HH;
  constexpr int f4n = (H * W) / 4;
  for (int i4 = (int)threadIdx.x; i4 < f4n; i4 += 512) {
    float4 v = reinterpret_cast<const float4*>(ch)[i4];
#pragma unroll
    for (int j = 0; j < 4; j++) {
      int idx = i4 * 4 + j;
      int h = idx / W, w = idx - h * W;  // compile-time magic div
      bool ok = h > 0 && h < (H - 1) && w > 0 && w < (W - 1);
      float f = (j == 0) ? v.x : (j == 1) ? v.y : (j == 2) ? v.z : v.w;
      if (ok) { mn = fminf(mn, f); mx = fmaxf(mx, f); }
    }
  }
}

// ---------------- K1 pass B: dual 6-bin hist + nibble write (interior only) ----------------
// u64 accumulators, 6 x 10-bit fields; per-lane counts <= 100 (H=224 @512thr) < 1023.
template <int HH>
__device__ __forceinline__ void histB(const float* __restrict__ ch, unsigned short* __restrict__ nb,
                                      float mn, float invd, ull& cbin, ull& clut) {
  constexpr int W = HH, H = HH;
  constexpr int f4n = (H * W) / 4;
  for (int i4 = (int)threadIdx.x; i4 < f4n; i4 += 512) {
    float4 v = reinterpret_cast<const float4*>(ch)[i4];
    unsigned pack = 0;
#pragma unroll
    for (int j = 0; j < 4; j++) {
      int idx = i4 * 4 + j;
      int h = idx / W, w = idx - h * W;
      bool intr = h > 0 && h < (H - 1) && w > 0 && w < (W - 1);
      float f = (j == 0) ? v.x : (j == 1) ? v.y : (j == 2) ? v.z : v.w;
      float vv = (f - mn) * invd * 256.0f;
      int bin = (int)(vv * 0.0234375f);  // * (6/256)
      bin = bin < 0 ? 0 : (bin > 5 ? 5 : bin);
      float tt = vv * 6.0f - 1.0f;
      int li = (int)tt;                  // trunc toward zero, matches astype(int32)
      li = li < 0 ? 0 : (li > 5 ? 5 : li);
      cbin += (ull)intr << (bin * 10);
      clut += (ull)intr << (li * 10);
      pack |= (unsigned)(intr ? li : 7) << (4 * j);  // border -> LUT slot 7
    }
    nb[i4] = (unsigned short)pack;
  }
}

// ---------------- per-channel LUT math (hh = full-mask dual histograms) ----------------
__device__ __forceinline__ void lutMath(int c, int H, int HW, float mn, float invd,
                                        unsigned* hh, float* LUT /*[7]*/) {
  float fHW = (float)HW;
  int nbp = 4 * H - 4;  // border pixel count (W==H)
  float vb = (0.f - mn) * invd * 256.0f;
  int bin_b = (int)(vb * 0.0234375f);
  bin_b = bin_b < 0 ? 0 : (bin_b > 5 ? 5 : bin_b);
  float ttb = vb * 6.0f - 1.0f;
  int lib = (int)ttb;
  lib = lib < 0 ? 0 : (lib > 5 ? 5 : lib);
  hh[bin_b] += (unsigned)nbp;   // reconstruct full-mask histograms (border value 0)
  hh[6 + lib] += (unsigned)nbp;
  float hl[6];
#pragma unroll
  for (int j = 0; j < 6; j++) hl[j] = -logf((float)hh[j] / fHW + 1e-4f);
  float mn2 = INFINITY, mx2 = -INFINITY, sum2 = 0.f;
#pragma unroll
  for (int j = 0; j < 6; j++) {
    unsigned cc = hh[6 + j];
    if (cc) { mn2 = fminf(mn2, hl[j]); mx2 = fmaxf(mx2, hl[j]); sum2 += (float)cc * hl[j]; }
  }
  float d2 = mx2 - mn2;
  float RL[6];
  if (d2 > 0.f) {
    float meanN = (sum2 / fHW - mn2) / d2;
    float w = 1.0f - meanN; w *= w;
#pragma unroll
    for (int j = 0; j < 6; j++) RL[j] = (hl[j] - mn2) / d2 * w;
  } else {
#pragma unroll
    for (int j = 0; j < 6; j++) RL[j] = 0.f;
  }
  if (c == 0) {
    float mnr = INFINITY, mxr = -INFINITY, sumr = 0.f;
#pragma unroll
    for (int j = 0; j < 6; j++) {
      unsigned cc = hh[6 + j];
      if (cc) { mnr = fminf(mnr, RL[j]); mxr = fmaxf(mxr, RL[j]); sumr += (float)cc * RL[j]; }
    }
    float dr = mxr - mnr;
    if (dr > 0.f) {
      float meanr = sumr / fHW;
      float wp = mxr - meanr; wp *= wp;
#pragma unroll
      for (int j = 0; j < 6; j++) LUT[j] = (RL[j] - mnr) / dr * wp;
      LUT[6] = LUT[lib];
    } else {
#pragma unroll
      for (int j = 0; j < 7; j++) LUT[j] = 0.f;
    }
  } else {
    float mnr = 0.f, mxr = 0.f, sumr = 0.f;
#pragma unroll
    for (int j = 0; j < 6; j++) {
      int cc = (int)hh[6 + j] - (j == lib ? nbp : 0);
      if (cc > 0) { mnr = fminf(mnr, RL[j]); mxr = fmaxf(mxr, RL[j]); sumr += (float)cc * RL[j]; }
    }
    float dr = mxr - mnr;
    if (dr > 0.f) {
      float meanr = sumr / fHW;
      float wp = mxr - meanr; wp *= wp;
#pragma unroll
      for (int j = 0; j < 6; j++) LUT[j] = (RL[j] - mnr) / dr * wp;
      LUT[6] = (0.f - mnr) / dr * wp;
    } else {
#pragma unroll
      for (int j = 0; j < 7; j++) LUT[j] = 0.f;
    }
  }
}

// ---------------- K1: one block per channel: minmax + hist + nibble + LUT ----------------
__global__ __launch_bounds__(512) void k_chan(Meta m, unsigned short* __restrict__ nib,
                                              float* __restrict__ lutg) {
  int b = blockIdx.x;
  int t = segOf(m.chanOff, b);
  int c = b - m.chanOff[t];
  int H = m.H[t], HW = H * H;
  const float* ch = m.x[t] + (size_t)c * HW;
  int tid = threadIdx.x, wid = tid >> 6, lane = tid & 63;

  // pass A: interior min/max
  float mn = INFINITY, mx = -INFINITY;
  switch (H) {
    case 224: mmA<224>(ch, mn, mx); break;
    case 112: mmA<112>(ch, mn, mx); break;
    case 56:  mmA<56>(ch, mn, mx); break;
    case 28:  mmA<28>(ch, mn, mx); break;
    default:  mmA<14>(ch, mn, mx); break;
  }
#pragma unroll
  for (int o = 32; o > 0; o >>= 1) {
    mn = fminf(mn, __shfl_down(mn, o));
    mx = fmaxf(mx, __shfl_down(mx, o));
  }
  __shared__ float smn[8], smx[8];
  __shared__ float sMn, sInv;
  if (lane == 0) { smn[wid] = mn; smx[wid] = mx; }
  __syncthreads();
  if (tid == 0) {
    for (int i = 1; i < 8; i++) { mn = fminf(mn, smn[i]); mx = fmaxf(mx, smx[i]); }
    mn = fminf(mn, 0.f); mx = fmaxf(mx, 0.f);   // fold border zeros
    float d = mx - mn;
    sMn = mn; sInv = d > 0.f ? 1.0f / d : 0.f;
  }
  __syncthreads();
  float mnc = sMn, invd = sInv;

  // pass B: histograms + nibble cache (L2-hot re-read)
  unsigned short* nb = nib + m.nibOff[t] + (size_t)c * (HW >> 2);
  ull cbin = 0ull, clut = 0ull;
  switch (H) {
    case 224: histB<224>(ch, nb, mnc, invd, cbin, clut); break;
    case 112: histB<112>(ch, nb, mnc, invd, cbin, clut); break;
    case 56:  histB<56>(ch, nb, mnc, invd, cbin, clut); break;
    case 28:  histB<28>(ch, nb, mnc, invd, cbin, clut); break;
    default:  histB<14>(ch, nb, mnc, invd, cbin, clut); break;
  }
  // pack lo|hi 16-bit per bin; per-wave sum <= 6400, cross-wave <= 49284 -> no carry
  unsigned pk[6];
#pragma unroll
  for (int j = 0; j < 6; j++)
    pk[j] = (unsigned)((cbin >> (10 * j)) & 1023ull) |
            ((unsigned)((clut >> (10 * j)) & 1023ull) << 16);
#pragma unroll
  for (int o = 32; o > 0; o >>= 1) {
#pragma unroll
    for (int j = 0; j < 6; j++) pk[j] += __shfl_down(pk[j], o);
  }
  __shared__ unsigned spk[8][6];
  if (lane == 0) {
#pragma unroll
    for (int j = 0; j < 6; j++) spk[wid][j] = pk[j];
  }
  __syncthreads();
  if (tid == 0) {
    unsigned hh[12];
#pragma unroll
    for (int j = 0; j < 6; j++) {
      unsigned s = 0;
#pragma unroll
      for (int w = 0; w < 8; w++) s += spk[w][j];
      hh[j] = s & 0xffffu; hh[6 + j] = s >> 16;
    }
    float LUT[7];
    lutMath(c, H, HW, mnc, invd, hh, LUT);
    float* o = lutg + (size_t)b * 8;
#pragma unroll
    for (int j = 0; j < 6; j++) o[j] = LUT[j];
    o[6] = LUT[6]; o[7] = LUT[6];   // slot 7 = border
  }
}

// ---------------- K2: p map from nibble cache (LUTs in LDS) ----------------
__global__ __launch_bounds__(256) void k_pmap(Meta m, const unsigned short* __restrict__ nib,
                                              const float* __restrict__ lutg,
                                              float* __restrict__ pmaps, float* __restrict__ ppart) {
  __shared__ float sLut[512 * 8];   // 16 KB
  __shared__ float sAcc[4][256];
  int b = blockIdx.x;
  int t = segOf(m.pmOff, b);
  int blk = b - m.pmOff[t];
  int C = m.C[t], HW = m.H[t] * m.H[t], i4n = HW >> 2;
  int tid = threadIdx.x, wid = tid >> 6, lane = tid & 63;
  const float4* Lg = reinterpret_cast<const float4*>(lutg + (size_t)m.chanOff[t] * 8);
  for (int i = tid; i < C * 2; i += 256) reinterpret_cast<float4*>(sLut)[i] = Lg[i];
  __syncthreads();
  int i4 = blk * 64 + lane;
  bool act = i4 < i4n;
  float a0 = 0.f, a1 = 0.f, a2 = 0.f, a3 = 0.f;
  if (act) {
    const unsigned short* nb = nib + m.nibOff[t] + i4;
    int cpw = C >> 2;
    int c0 = wid * cpw, c1 = c0 + cpw;
#pragma unroll 4
    for (int c = c0; c < c1; ++c) {
      unsigned n = nb[(size_t)c * i4n];
      a0 += sLut[c * 8 + (int)(n & 7u)];
      a1 += sLut[c * 8 + (int)((n >> 4) & 7u)];
      a2 += sLut[c * 8 + (int)((n >> 8) & 7u)];
      a3 += sLut[c * 8 + (int)((n >> 12) & 7u)];
    }
  }
  *reinterpret_cast<float4*>(&sAcc[wid][lane * 4]) = make_float4(a0, a1, a2, a3);
  __syncthreads();
  if (wid == 0) {
    float bmn = INFINITY, bmx = -INFINITY;
    if (act) {
      float t0 = 0.f, t1 = 0.f, t2 = 0.f, t3 = 0.f;
#pragma unroll
      for (int w = 0; w < 4; w++) {   // ascending w == ascending channel blocks (ref order)
        const float* s = &sAcc[w][lane * 4];
        t0 += s[0]; t1 += s[1]; t2 += s[2]; t3 += s[3];
      }
      *reinterpret_cast<float4*>(pmaps + (size_t)m.pixOff[t] + (size_t)i4 * 4) =
          make_float4(t0, t1, t2, t3);
      bmn = fminf(fminf(t0, t1), fminf(t2, t3));
      bmx = fmaxf(fmaxf(t0, t1), fmaxf(t2, t3));
    }
#pragma unroll
    for (int o = 32; o > 0; o >>= 1) {
      bmn = fminf(bmn, __shfl_down(bmn, o));
      bmx = fmaxf(bmx, __shfl_down(bmx, o));
    }
    if (lane == 0) { ppart[2 * b] = bmn; ppart[2 * b + 1] = bmx; }
  }
}

// ---------------- K3: bilinear resize + norm; per-block (mn,mx,sum) partials ----------------
__global__ __launch_bounds__(256) void k_resize(Meta m, const float* pmaps, const float* ppart,
                                                float* mmaps, float* rpart) {
  __shared__ float sMnT, sInvT;
  int t = blockIdx.x / 225;
  int blk = blockIdx.x % 225;
  int wid = threadIdx.x >> 6, lane = threadIdx.x & 63;
  if (wid == 0) {
    int n = m.pmOff[t + 1] - m.pmOff[t];        // <= 196 partials
    const float* pp = ppart + (size_t)m.pmOff[t] * 2;
    float mn = INFINITY, mx = -INFINITY;
    for (int i = lane; i < n; i += 64) { mn = fminf(mn, pp[2 * i]); mx = fmaxf(mx, pp[2 * i + 1]); }
#pragma unroll
    for (int o = 32; o > 0; o >>= 1) {
      mn = fminf(mn, __shfl_down(mn, o));
      mx = fmaxf(mx, __shfl_down(mx, o));
    }
    if (lane == 0) {
      float d = mx - mn;
      sMnT = mn; sInvT = d > 0.f ? 1.0f / d : 0.f;
    }
  }
  __syncthreads();
  int pix = blk * 256 + threadIdx.x;  // 225*256 == 57600 exactly
  int H = m.H[t], W = m.H[t];
  const float* p = pmaps + m.pixOff[t];
  float mn = sMnT, a = sInvT;
  int oy = pix / 240, ox = pix - oy * 240;
  float hs = m.hsc[t];
  float sy = ((float)oy + 0.5f) * hs - 0.5f;
  float sx = ((float)ox + 0.5f) * hs - 0.5f;
  float fy0 = floorf(sy), fx0 = floorf(sx);
  float fy = sy - fy0, fx = sx - fx0;
  int iy0 = (int)fy0, ix0 = (int)fx0;
  int y0 = iy0 < 0 ? 0 : (iy0 > H - 1 ? H - 1 : iy0);
  int y1 = iy0 + 1 < 0 ? 0 : (iy0 + 1 > H - 1 ? H - 1 : iy0 + 1);
  int x0 = ix0 < 0 ? 0 : (ix0 > W - 1 ? W - 1 : ix0);
  int x1 = ix0 + 1 < 0 ? 0 : (ix0 + 1 > W - 1 ? W - 1 : ix0 + 1);
  float v00 = p[y0 * W + x0], v01 = p[y0 * W + x1];
  float v10 = p[y1 * W + x0], v11 = p[y1 * W + x1];
  float r = (1.f - fy) * ((1.f - fx) * v00 + fx * v01) + fy * ((1.f - fx) * v10 + fx * v11);
  float mv = (r - mn) * a;
  mmaps[(size_t)t * RHW + pix] = mv;
  float bmn = mv, bmx = mv, bsm = mv;
#pragma unroll
  for (int o = 32; o > 0; o >>= 1) {
    bmn = fminf(bmn, __shfl_down(bmn, o));
    bmx = fmaxf(bmx, __shfl_down(bmx, o));
    bsm += __shfl_down(bsm, o);
  }
  __shared__ float smn[4], smx[4], ssm[4];
  if ((threadIdx.x & 63) == 0) { smn[wid] = bmn; smx[wid] = bmx; ssm[wid] = bsm; }
  __syncthreads();
  if (threadIdx.x == 0) {
    for (int i = 1; i < 4; i++) { bmn = fminf(bmn, smn[i]); bmx = fmaxf(bmx, smx[i]); bsm += ssm[i]; }
    float* rp = rpart + ((size_t)t * 225 + blk) * 3;
    rp[0] = bmn; rp[1] = bmx; rp[2] = bsm;
  }
}

// ---------------- K4: fuse group (inline partial reduce) ----------------
__global__ __launch_bounds__(256) void k_fuse(const float* mmaps, const float* rpart,
                                              float* fusedm, float* fpart) {
  __shared__ float sMn[3], sD[3], sW[3];
  int g = blockIdx.x / 225;
  int blk = blockIdx.x % 225;
  const int gs[6] = {0, 2, 4, 7, 10, 13};
  int nt = gs[g + 1] - gs[g];
  int wid = threadIdx.x >> 6, lane = threadIdx.x & 63;
  if (wid < nt) {
    int t = gs[g] + wid;
    const float* rp = rpart + (size_t)t * 225 * 3;
    float mn = INFINITY, mx = -INFINITY, sm = 0.f;
    for (int i = lane; i < 225; i += 64) {
      mn = fminf(mn, rp[3 * i]); mx = fmaxf(mx, rp[3 * i + 1]); sm += rp[3 * i + 2];
    }
#pragma unroll
    for (int o = 32; o > 0; o >>= 1) {
      mn = fminf(mn, __shfl_down(mn, o));
      mx = fmaxf(mx, __shfl_down(mx, o));
      sm += __shfl_down(sm, o);
    }
    if (lane == 0) {
      float d = mx - mn;
      if (d > 0.f) {
        float mean = sm * (1.0f / 57600.0f);
        float w = mx - mean; w *= w;
        sMn[wid] = mn; sD[wid] = d; sW[wid] = w;
      } else {
        sMn[wid] = 0.f; sD[wid] = 0.f; sW[wid] = 0.f;
      }
    }
  }
  __syncthreads();
  int pix = blk * 256 + threadIdx.x;
  float acc = 0.f;
  for (int k = 0; k < nt; k++) {
    int t = gs[g] + k;
    if (sD[k] > 0.f) acc += (mmaps[(size_t)t * RHW + pix] - sMn[k]) / sD[k] * sW[k];
  }
  fusedm[(size_t)g * RHW + pix] = acc;
  float bmn = acc, bmx = acc;
#pragma unroll
  for (int o = 32; o > 0; o >>= 1) {
    bmn = fminf(bmn, __shfl_down(bmn, o));
    bmx = fmaxf(bmx, __shfl_down(bmx, o));
  }
  __shared__ float smn[4], smx[4];
  if ((threadIdx.x & 63) == 0) { smn[wid] = bmn; smx[wid] = bmx; }
  __syncthreads();
  if (threadIdx.x == 0) {
    for (int i = 1; i < 4; i++) { bmn = fminf(bmn, smn[i]); bmx = fmaxf(bmx, smx[i]); }
    float* fp = fpart + ((size_t)g * 225 + blk) * 2;
    fp[0] = bmn; fp[1] = bmx;
  }
}

// ---------------- K5: final outputs (inline fstats reduce) ----------------
__global__ __launch_bounds__(256) void k_out(const float* fusedm, const float* fpart, float* out) {
  __shared__ float fmn[5], finv[5];
  int wid = threadIdx.x >> 6, lane = threadIdx.x & 63;
  for (int g = wid; g < 5; g += 4) {
    const float* fp = fpart + (size_t)g * 225 * 2;
    float mn = INFINITY, mx = -INFINITY;
    for (int i = lane; i < 225; i += 64) {
      mn = fminf(mn, fp[2 * i]); mx = fmaxf(mx, fp[2 * i + 1]);
    }
#pragma unroll
    for (int o = 32; o > 0; o >>= 1) {
      mn = fminf(mn, __shfl_down(mn, o));
      mx = fmaxf(mx, __shfl_down(mx, o));
    }
    if (lane == 0) {
      float d = mx - mn;
      fmn[g] = mn; finv[g] = d > 0.f ? 256.0f / d : 0.f;
    }
  }
  __syncthreads();
  int pix = blockIdx.x * 256 + threadIdx.x;
  float acc = 0.f;
  float* out2 = out + RHW;
#pragma unroll
  for (int g = 0; g < 5; g++) {
    float v = (fusedm[(size_t)g * RHW + pix] - fmn[g]) * finv[g];
    out2[(size_t)pix * 5 + g] = v;
    acc += v;
  }
  out[pix] = acc;
}

extern "C" void kernel_launch(void* const* d_in, const int* in_sizes, int n_in,
                              void* d_out, int out_size, void* d_ws, size_t ws_size,
                              hipStream_t stream) {
  static const int Cs[NT] = {64, 64, 128, 128, 256, 256, 256, 512, 512, 512, 512, 512, 512};
  static const int Hs[NT] = {224, 224, 112, 112, 56, 56, 56, 28, 28, 28, 14, 14, 14};
  Meta m;
  int co = 0, po = 0, pmb = 0, nibTot = 0;
  for (int t = 0; t < NT; t++) {
    m.x[t] = (const float*)d_in[t];
    m.C[t] = Cs[t]; m.H[t] = Hs[t];
    m.hsc[t] = (float)((double)Hs[t] / 240.0);
    int HW = Hs[t] * Hs[t];
    m.chanOff[t] = co; co += Cs[t];
    m.pixOff[t] = po; po += HW;
    m.nibOff[t] = nibTot; nibTot += Cs[t] * (HW >> 2);
    m.pmOff[t] = pmb; pmb += (HW + 255) / 256;
  }
  m.chanOff[NT] = co; m.pixOff[NT] = po; m.pmOff[NT] = pmb;

  size_t off = 0;
  auto a16 = [](size_t x) { return (x + 15) & ~(size_t)15; };
#define WALLOC(var, type, count) type* var = (type*)((char*)d_ws + off); off = a16(off + sizeof(type) * (size_t)(count));
  WALLOC(nib, unsigned short, nibTot)
  WALLOC(lutg, float, 8 * co)
  WALLOC(ppart, float, 2 * pmb)
  WALLOC(rpart, float, NT * 225 * 3)
  WALLOC(fpart, float, 5 * 225 * 2)
  WALLOC(pmaps, float, po)
  WALLOC(mmaps, float, NT * RHW)
  WALLOC(fusedm, float, 5 * RHW)
#undef WALLOC

  hipLaunchKernelGGL(k_chan, dim3(co), dim3(512), 0, stream, m, nib, lutg);
  hipLaunchKernelGGL(k_pmap, dim3(pmb), dim3(256), 0, stream, m, nib, lutg, pmaps, ppart);
  hipLaunchKernelGGL(k_resize, dim3(NT * 225), dim3(256), 0, stream, m, pmaps, ppart, mmaps, rpart);
  hipLaunchKernelGGL(k_fuse, dim3(5 * 225), dim3(256), 0, stream, mmaps, rpart, fusedm, fpart);
  hipLaunchKernelGGL(k_out, dim3(225), dim3(256), 0, stream, fusedm, fpart, (float*)d_out);
}